// Round 12
// baseline (266.161 us; speedup 1.0000x reference)
//
#include <hip/hip_runtime.h>
#include <hip/hip_bf16.h>
#include <hip/hip_cooperative_groups.h>

namespace cg = cooperative_groups;

#define IN_DIM 128
#define OUT_DIM 64
#define FLOG 7                     // fine bucket: 128 nodes
#define FNPB (1 << FLOG)
#define MAXFINE 1024               // fine bins supported (n_nodes <= 128K)
#define GB 256                     // build grid blocks (co-resident)
#define CAP 4096                   // LDS sorted-edge capacity per fine bucket

static inline size_t align_up(size_t v, size_t a) { return (v + a - 1) & ~(a - 1); }

__device__ __forceinline__ unsigned short f2bf(float f) {
    unsigned int x = __float_as_uint(f);
    unsigned int r = (x + 0x7fffu + ((x >> 16) & 1u)) >> 16;  // RTNE
    return (unsigned short)r;
}

typedef _Float16 half8 __attribute__((ext_vector_type(8)));
typedef float f32x4 __attribute__((ext_vector_type(4)));

// ---------------------------------------------------------------------------
// kBuild (cooperative): the whole CSR build in one launch.
//  P1: per-block LDS fine histogram + device ticket atomics (LDS persists,
//      so no global tickets array).
//  P2: every block locally scans BinTotal -> LDS BucketStart; block 0
//      publishes the global copy for kF.
//  P3: scatter packed edges (row<<7)|(col&127) with LDS cursors.
//  P4: per-fine-bucket degree histogram -> dis = rsqrt(deg).
// Two grid.sync()s replace four kernel-boundary drains.
// ---------------------------------------------------------------------------
__global__ void __launch_bounds__(256) kBuild(
    const int* __restrict__ row, const int* __restrict__ col,
    int* __restrict__ BinTotal, int* __restrict__ BucketStart,
    unsigned int* __restrict__ EdgeBuf, float* __restrict__ dis,
    int n_nodes, int n_edges, int nbf, int chunk) {
    __shared__ int hist[MAXFINE];   // P1: counts -> tickets -> P3: cursors
    __shared__ int bs[MAXFINE];     // local exclusive BucketStart
    __shared__ int s[256];
    __shared__ int cnt[FNPB];
    int t = threadIdx.x;
    int start = blockIdx.x * chunk;
    int end = min(n_edges, start + chunk);

    // ---- P1: histogram own chunk ----
    for (int i = t; i < nbf; i += 256) hist[i] = 0;
    __syncthreads();
    for (int i = start + t; i < end; i += 256)
        atomicAdd(&hist[col[i] >> FLOG], 1);
    __syncthreads();
    // ticket: arrival-order exclusive base within each bin
    for (int i = t; i < nbf; i += 256)
        hist[i] = atomicAdd(&BinTotal[i], hist[i]);

    cg::this_grid().sync();

    // ---- P2: local exclusive scan of BinTotal (4 elems/thread) ----
    int v[4];
#pragma unroll
    for (int j = 0; j < 4; ++j) {
        int idx = t * 4 + j;
        v[j] = (idx < nbf) ? BinTotal[idx] : 0;
    }
    int tsum = v[0] + v[1] + v[2] + v[3];
    s[t] = tsum;
    __syncthreads();
    for (int off = 1; off < 256; off <<= 1) {
        int x = (t >= off) ? s[t - off] : 0;
        __syncthreads();
        s[t] += x;
        __syncthreads();
    }
    int run = s[t] - tsum;
#pragma unroll
    for (int j = 0; j < 4; ++j) {
        int idx = t * 4 + j;
        if (idx < nbf) {
            bs[idx] = run;
            if (blockIdx.x == 0) BucketStart[idx] = run;  // publish for kF
        }
        run += v[j];
    }
    if (blockIdx.x == 0 && t == 0) BucketStart[nbf] = n_edges;
    __syncthreads();
    // cursors = BucketStart + ticket
    for (int i = t; i < nbf; i += 256) hist[i] += bs[i];
    __syncthreads();

    // ---- P3: scatter ----
    for (int i = start + t; i < end; i += 256) {
        int c = col[i];
        int r = row[i];
        int p = atomicAdd(&hist[c >> FLOG], 1);
        EdgeBuf[p] = ((unsigned int)r << FLOG) | (unsigned int)(c & (FNPB - 1));
    }

    cg::this_grid().sync();

    // ---- P4: degree -> dis per fine bucket ----
    for (int b = blockIdx.x; b < nbf; b += GB) {
        int es = bs[b];
        int ee = (b + 1 < nbf) ? bs[b + 1] : n_edges;
        if (t < FNPB) cnt[t] = 0;
        __syncthreads();
        for (int i = es + t; i < ee; i += 256)
            atomicAdd(&cnt[EdgeBuf[i] & (FNPB - 1)], 1);
        __syncthreads();
        int node = (b << FLOG) + t;
        if (t < FNPB && node < n_nodes) {
            int d = cnt[t];
            dis[node] = (d > 0) ? rsqrtf((float)d) : 0.0f;
        }
        __syncthreads();  // protect cnt before next bucket
    }
}

// ---------------------------------------------------------------------------
// Non-cooperative fallback build (separate kernels, fine granularity)
// ---------------------------------------------------------------------------
__global__ void __launch_bounds__(256) kP1_ticket(
    const int* __restrict__ col, int* __restrict__ BinTotal,
    int* __restrict__ tickets, int n_edges, int nbf, int chunk) {
    __shared__ int hist[MAXFINE];
    int t = threadIdx.x;
    for (int i = t; i < nbf; i += 256) hist[i] = 0;
    __syncthreads();
    int start = blockIdx.x * chunk;
    int end = min(n_edges, start + chunk);
    for (int i = start + t; i < end; i += 256)
        atomicAdd(&hist[col[i] >> FLOG], 1);
    __syncthreads();
    int* trow = tickets + (size_t)blockIdx.x * nbf;
    for (int i = t; i < nbf; i += 256)
        trow[i] = atomicAdd(&BinTotal[i], hist[i]);
}

__global__ void __launch_bounds__(256) kP2_scan(
    const int* __restrict__ BinTotal, int* __restrict__ BucketStart,
    int nbf, int n_edges) {
    __shared__ int s[256];
    int t = threadIdx.x;
    int v[4];
#pragma unroll
    for (int j = 0; j < 4; ++j) {
        int idx = t * 4 + j;
        v[j] = (idx < nbf) ? BinTotal[idx] : 0;
    }
    int tsum = v[0] + v[1] + v[2] + v[3];
    s[t] = tsum;
    __syncthreads();
    for (int off = 1; off < 256; off <<= 1) {
        int x = (t >= off) ? s[t - off] : 0;
        __syncthreads();
        s[t] += x;
        __syncthreads();
    }
    int run = s[t] - tsum;
#pragma unroll
    for (int j = 0; j < 4; ++j) {
        int idx = t * 4 + j;
        if (idx < nbf) BucketStart[idx] = run;
        run += v[j];
    }
    if (t == 0) BucketStart[nbf] = n_edges;
}

__global__ void __launch_bounds__(256) kP3_scatter(
    const int* __restrict__ row, const int* __restrict__ col,
    const int* __restrict__ BucketStart, const int* __restrict__ tickets,
    unsigned int* __restrict__ EdgeBuf, int n_edges, int nbf, int chunk) {
    __shared__ int cur[MAXFINE];
    const int* trow = tickets + (size_t)blockIdx.x * nbf;
    int t = threadIdx.x;
    for (int i = t; i < nbf; i += 256)
        cur[i] = BucketStart[i] + trow[i];
    __syncthreads();
    int start = blockIdx.x * chunk;
    int end = min(n_edges, start + chunk);
    for (int i = start + t; i < end; i += 256) {
        int c = col[i];
        int r = row[i];
        int p = atomicAdd(&cur[c >> FLOG], 1);
        EdgeBuf[p] = ((unsigned int)r << FLOG) | (unsigned int)(c & (FNPB - 1));
    }
}

__global__ void __launch_bounds__(256) kP4_degree(
    const unsigned int* __restrict__ EdgeBuf, const int* __restrict__ BucketStart,
    float* __restrict__ dis, int n_nodes) {
    __shared__ int cnt[FNPB];
    int t = threadIdx.x;
    if (t < FNPB) cnt[t] = 0;
    __syncthreads();
    int es = BucketStart[blockIdx.x];
    int ee = BucketStart[blockIdx.x + 1];
    for (int i = es + t; i < ee; i += 256)
        atomicAdd(&cnt[EdgeBuf[i] & (FNPB - 1)], 1);
    __syncthreads();
    int node = (blockIdx.x << FLOG) + t;
    if (t < FNPB && node < n_nodes) {
        int d = cnt[t];
        dis[node] = (d > 0) ? rsqrtf((float)d) : 0.0f;
    }
}

// ---------------------------------------------------------------------------
// k_matmul_mfma: h(bf16) = (x @ W) * dis via f16 MFMA 16x16x32.
// One wave per 16-node tile; W fragments hoisted; no LDS/barriers.
// ---------------------------------------------------------------------------
__global__ void __launch_bounds__(256) k_matmul_mfma(
    const float* __restrict__ x, const float* __restrict__ W,
    const float* __restrict__ dis, unsigned short* __restrict__ h, int n_nodes) {
    const int lane = threadIdx.x & 63;
    const int m = lane & 15;
    const int q = lane >> 4;
    const int wid = (blockIdx.x * blockDim.x + threadIdx.x) >> 6;
    const int ntiles = (n_nodes + 15) >> 4;
    if (wid >= ntiles) return;

    half8 bfrag[4][4];
#pragma unroll
    for (int kt = 0; kt < 4; ++kt) {
#pragma unroll
        for (int nt = 0; nt < 4; ++nt) {
            int k0 = kt * 32 + q * 8;
            int c = nt * 16 + m;
#pragma unroll
            for (int j = 0; j < 8; ++j)
                bfrag[kt][nt][j] = (_Float16)W[(size_t)(k0 + j) * OUT_DIM + c];
        }
    }

    const int nb = wid << 4;
    int arow = nb + m;
    if (arow >= n_nodes) arow = n_nodes - 1;
    const float* xr = x + (size_t)arow * IN_DIM;

    f32x4 acc[4];
#pragma unroll
    for (int nt = 0; nt < 4; ++nt) acc[nt] = (f32x4){0.f, 0.f, 0.f, 0.f};

#pragma unroll
    for (int kt = 0; kt < 4; ++kt) {
        const float4* xp = (const float4*)(xr + kt * 32 + q * 8);
        float4 lo = xp[0];
        float4 hi = xp[1];
        half8 afrag;
        afrag[0] = (_Float16)lo.x; afrag[1] = (_Float16)lo.y;
        afrag[2] = (_Float16)lo.z; afrag[3] = (_Float16)lo.w;
        afrag[4] = (_Float16)hi.x; afrag[5] = (_Float16)hi.y;
        afrag[6] = (_Float16)hi.z; afrag[7] = (_Float16)hi.w;
#pragma unroll
        for (int nt = 0; nt < 4; ++nt)
            acc[nt] = __builtin_amdgcn_mfma_f32_16x16x32_f16(afrag, bfrag[kt][nt],
                                                             acc[nt], 0, 0, 0);
    }

#pragma unroll
    for (int r = 0; r < 4; ++r) {
        int node = nb + q * 4 + r;
        if (node < n_nodes) {
            float dv = dis[node];
            unsigned short* hp = h + (size_t)node * OUT_DIM + m;
#pragma unroll
            for (int nt = 0; nt < 4; ++nt)
                hp[nt * 16] = f2bf(acc[nt][r] * dv);
        }
    }
}

// ---------------------------------------------------------------------------
// kF: fused per-fine-bucket local sort (into LDS) + gather-aggregate.
// Round-10 proven form (no filter). Int LDS atomics only.
// ---------------------------------------------------------------------------
__global__ void __launch_bounds__(512) kF_sortagg(
    const unsigned int* __restrict__ EdgeBuf, const int* __restrict__ BucketStart,
    const float* __restrict__ dis, const unsigned short* __restrict__ h,
    const float* __restrict__ b, float* __restrict__ out,
    int* __restrict__ spill, int* __restrict__ spillcur, int n_nodes) {
    __shared__ int cnt[FNPB];
    __shared__ int seg[FNPB];
    __shared__ int cursor[FNPB];
    __shared__ int sbuf[CAP];
    __shared__ int sbase_sh;
    int t = threadIdx.x;
    int es = BucketStart[blockIdx.x];
    int ee = BucketStart[blockIdx.x + 1];
    int ne = ee - es;
    int nb0 = blockIdx.x << FLOG;

    if (t < FNPB) cnt[t] = 0;
    __syncthreads();
    for (int i = es + t; i < ee; i += 512)
        atomicAdd(&cnt[EdgeBuf[i] & (FNPB - 1)], 1);
    __syncthreads();

    if (t < FNPB) seg[t] = cnt[t];
    __syncthreads();
    for (int off = 1; off < FNPB; off <<= 1) {
        int x = 0;
        if (t < FNPB && t >= off) x = seg[t - off];
        __syncthreads();
        if (t < FNPB) seg[t] += x;
        __syncthreads();
    }
    if (t < FNPB) cursor[t] = seg[t] - cnt[t];
    __syncthreads();

    if (t == 0 && ne > CAP) sbase_sh = atomicAdd(spillcur, ne);
    __syncthreads();

    const int lane = t & 63;
    const int wv = t >> 6;
    const int quarter = lane >> 4;
    const int qlane = lane & 15;
    float4 bias = ((const float4*)b)[qlane];

    if (ne <= CAP) {
        for (int i = es + t; i < ee; i += 512) {
            unsigned int v = EdgeBuf[i];
            int p = atomicAdd(&cursor[v & (FNPB - 1)], 1);
            sbuf[p] = (int)(v >> FLOG);
        }
        __syncthreads();

        for (int nl = wv; nl < FNPB; nl += 8) {
            int node = nb0 + nl;
            if (node >= n_nodes) break;
            int e_ = seg[nl];
            int s_ = e_ - cnt[nl];
            float a0 = 0.f, a1 = 0.f, a2 = 0.f, a3 = 0.f;
            for (int j0 = s_; j0 < e_; j0 += 8) {
                int iA = j0 + quarter;
                int iB = j0 + quarter + 4;
                int rA = sbuf[iA < e_ ? iA : s_];
                int rB = sbuf[iB < e_ ? iB : s_];
                uint2 vA = make_uint2(0u, 0u), vB = make_uint2(0u, 0u);
                if (iA < e_)
                    vA = *(const uint2*)(h + (size_t)rA * OUT_DIM + qlane * 4);
                if (iB < e_)
                    vB = *(const uint2*)(h + (size_t)rB * OUT_DIM + qlane * 4);
                a0 += __uint_as_float(vA.x << 16);
                a1 += __uint_as_float(vA.x & 0xFFFF0000u);
                a2 += __uint_as_float(vA.y << 16);
                a3 += __uint_as_float(vA.y & 0xFFFF0000u);
                a0 += __uint_as_float(vB.x << 16);
                a1 += __uint_as_float(vB.x & 0xFFFF0000u);
                a2 += __uint_as_float(vB.y << 16);
                a3 += __uint_as_float(vB.y & 0xFFFF0000u);
            }
            a0 += __shfl_xor(a0, 16, 64); a0 += __shfl_xor(a0, 32, 64);
            a1 += __shfl_xor(a1, 16, 64); a1 += __shfl_xor(a1, 32, 64);
            a2 += __shfl_xor(a2, 16, 64); a2 += __shfl_xor(a2, 32, 64);
            a3 += __shfl_xor(a3, 16, 64); a3 += __shfl_xor(a3, 32, 64);
            if (quarter == 0) {
                float dv = dis[node];
                float4 o;
                o.x = fmaxf(fmaf(a0, dv, bias.x), 0.f);
                o.y = fmaxf(fmaf(a1, dv, bias.y), 0.f);
                o.z = fmaxf(fmaf(a2, dv, bias.z), 0.f);
                o.w = fmaxf(fmaf(a3, dv, bias.w), 0.f);
                ((float4*)(out + (size_t)node * OUT_DIM))[qlane] = o;
            }
        }
    } else {
        int sbase = sbase_sh;
        for (int i = es + t; i < ee; i += 512) {
            unsigned int v = EdgeBuf[i];
            int p = atomicAdd(&cursor[v & (FNPB - 1)], 1);
            spill[sbase + p] = (int)(v >> FLOG);
        }
        __threadfence();
        __syncthreads();
        for (int nl = wv; nl < FNPB; nl += 8) {
            int node = nb0 + nl;
            if (node >= n_nodes) break;
            int e_ = seg[nl];
            int s_ = e_ - cnt[nl];
            float a0 = 0.f, a1 = 0.f, a2 = 0.f, a3 = 0.f;
            for (int j0 = s_; j0 < e_; j0 += 8) {
                int iA = j0 + quarter;
                int iB = j0 + quarter + 4;
                int rA = spill[sbase + (iA < e_ ? iA : s_)];
                int rB = spill[sbase + (iB < e_ ? iB : s_)];
                uint2 vA = make_uint2(0u, 0u), vB = make_uint2(0u, 0u);
                if (iA < e_)
                    vA = *(const uint2*)(h + (size_t)rA * OUT_DIM + qlane * 4);
                if (iB < e_)
                    vB = *(const uint2*)(h + (size_t)rB * OUT_DIM + qlane * 4);
                a0 += __uint_as_float(vA.x << 16);
                a1 += __uint_as_float(vA.x & 0xFFFF0000u);
                a2 += __uint_as_float(vA.y << 16);
                a3 += __uint_as_float(vA.y & 0xFFFF0000u);
                a0 += __uint_as_float(vB.x << 16);
                a1 += __uint_as_float(vB.x & 0xFFFF0000u);
                a2 += __uint_as_float(vB.y << 16);
                a3 += __uint_as_float(vB.y & 0xFFFF0000u);
            }
            a0 += __shfl_xor(a0, 16, 64); a0 += __shfl_xor(a0, 32, 64);
            a1 += __shfl_xor(a1, 16, 64); a1 += __shfl_xor(a1, 32, 64);
            a2 += __shfl_xor(a2, 16, 64); a2 += __shfl_xor(a2, 32, 64);
            a3 += __shfl_xor(a3, 16, 64); a3 += __shfl_xor(a3, 32, 64);
            if (quarter == 0) {
                float dv = dis[node];
                float4 o;
                o.x = fmaxf(fmaf(a0, dv, bias.x), 0.f);
                o.y = fmaxf(fmaf(a1, dv, bias.y), 0.f);
                o.z = fmaxf(fmaf(a2, dv, bias.z), 0.f);
                o.w = fmaxf(fmaf(a3, dv, bias.w), 0.f);
                ((float4*)(out + (size_t)node * OUT_DIM))[qlane] = o;
            }
        }
    }
}

// ---------------------------------------------------------------------------
// Last-resort fallback (exotic sizes): atomic scatter, fp32 h
// ---------------------------------------------------------------------------
#define MM_NODES 16
__global__ void __launch_bounds__(256) k_matmul_f32(
    const float* __restrict__ x, const float* __restrict__ W,
    const float* __restrict__ dis, float* __restrict__ h, int n_nodes) {
    __shared__ float xs[MM_NODES * IN_DIM];
    const int lane = threadIdx.x & 63;
    const int wv = threadIdx.x >> 6;
    float w[IN_DIM];
#pragma unroll
    for (int k = 0; k < IN_DIM; ++k) w[k] = W[k * OUT_DIM + lane];
    int nchunks = (n_nodes + MM_NODES - 1) / MM_NODES;
    for (int ch = blockIdx.x; ch < nchunks; ch += gridDim.x) {
        int base = ch * MM_NODES;
        int nrows = min(MM_NODES, n_nodes - base);
        __syncthreads();
        const float4* xg = (const float4*)(x + (size_t)base * IN_DIM);
        int nf4 = nrows * IN_DIM / 4;
        for (int i = threadIdx.x; i < nf4; i += 256) ((float4*)xs)[i] = xg[i];
        __syncthreads();
#pragma unroll
        for (int j = 0; j < 4; ++j) {
            int local = wv * 4 + j;
            int node = base + local;
            if (local < nrows) {
                const float4* xr = (const float4*)(xs + local * IN_DIM);
                float acc = 0.0f;
#pragma unroll
                for (int k4 = 0; k4 < IN_DIM / 4; ++k4) {
                    float4 xv = xr[k4];
                    acc = fmaf(xv.x, w[k4 * 4 + 0], acc);
                    acc = fmaf(xv.y, w[k4 * 4 + 1], acc);
                    acc = fmaf(xv.z, w[k4 * 4 + 2], acc);
                    acc = fmaf(xv.w, w[k4 * 4 + 3], acc);
                }
                h[(size_t)node * OUT_DIM + lane] = acc * dis[node];
            }
        }
    }
}

__global__ void k_degree_fb(const int* __restrict__ col, int* __restrict__ deg,
                            int n_edges) {
    int i = blockIdx.x * blockDim.x + threadIdx.x;
    int stride = gridDim.x * blockDim.x;
    for (; i < n_edges; i += stride) atomicAdd(&deg[col[i]], 1);
}

__global__ void k_rsqrt_fb(const int* __restrict__ deg, float* __restrict__ dis, int n) {
    int i = blockIdx.x * blockDim.x + threadIdx.x;
    if (i < n) {
        int d = deg[i];
        dis[i] = (d > 0) ? rsqrtf((float)d) : 0.0f;
    }
}

__global__ void __launch_bounds__(256) k_scatter_fb(
    const int* __restrict__ row, const int* __restrict__ col,
    const float* __restrict__ dis, const float* __restrict__ h,
    float* __restrict__ out, int n_edges) {
    const int lane = threadIdx.x & 63;
    int e = (blockIdx.x * blockDim.x + threadIdx.x) >> 6;
    int nw = (gridDim.x * blockDim.x) >> 6;
    for (; e < n_edges; e += nw) {
        int r = row[e];
        int c = col[e];
        float v = h[(size_t)r * OUT_DIM + lane] * dis[c];
        atomicAdd(&out[(size_t)c * OUT_DIM + lane], v);
    }
}

__global__ void k_bias_relu_fb(float* __restrict__ out, const float* __restrict__ b,
                               int total) {
    int i = blockIdx.x * blockDim.x + threadIdx.x;
    int stride = gridDim.x * blockDim.x;
    for (; i < total; i += stride) {
        float v = out[i] + b[i & (OUT_DIM - 1)];
        out[i] = fmaxf(v, 0.0f);
    }
}

extern "C" void kernel_launch(void* const* d_in, const int* in_sizes, int n_in,
                              void* d_out, int out_size, void* d_ws, size_t ws_size,
                              hipStream_t stream) {
    const float* x = (const float*)d_in[0];
    const int* ei = (const int*)d_in[1];  // [2, E] int32
    const float* W = (const float*)d_in[2];
    const float* b = (const float*)d_in[3];
    float* out = (float*)d_out;

    const int n_nodes = in_sizes[0] / IN_DIM;
    const int n_edges = in_sizes[1] / 2;
    const int* row = ei;
    const int* col = ei + n_edges;

    const int nbf = (n_nodes + FNPB - 1) >> FLOG;   // fine buckets
    const int chunk = (n_edges + GB - 1) / GB;

    // ---- workspace layout ----
    char* wsb = (char*)d_ws;
    size_t off = 0;
    int* BinTotal = (int*)(wsb + off);   off += align_up((size_t)(nbf + 8) * 4, 256);
    int* spillcur = BinTotal + nbf;      // zeroed by same memset
    int* BucketStart = (int*)(wsb + off);off += align_up((size_t)(nbf + 1) * 4, 256);
    int* tickets = (int*)(wsb + off);    off += align_up((size_t)GB * nbf * 4, 256);
    float* dis = (float*)(wsb + off);    off += align_up((size_t)n_nodes * 4, 256);
    unsigned int* EdgeBuf = (unsigned int*)(wsb + off);
                                         off += align_up((size_t)n_edges * 4, 256);
    int* spill = (int*)(wsb + off);      off += align_up((size_t)n_edges * 4, 256);
    unsigned short* h = (unsigned short*)(wsb + off);
                                         off += (size_t)n_nodes * OUT_DIM * 2;
    const size_t needed = off;

    const bool ok = (ws_size >= needed) && (nbf <= MAXFINE) &&
                    (n_nodes <= (1 << 24));  // row fits in 32-7=25 bits

    if (ok) {
        int coop = 0;
        int dev = 0;
        hipGetDevice(&dev);
        hipDeviceGetAttribute(&coop, hipDeviceAttributeCooperativeLaunch, dev);

        hipMemsetAsync(BinTotal, 0, (size_t)(nbf + 8) * 4, stream);
        if (coop) {
            const int* row_a = row;
            const int* col_a = col;
            int* bt_a = BinTotal;
            int* bs_a = BucketStart;
            unsigned int* eb_a = EdgeBuf;
            float* dis_a = dis;
            int nn_a = n_nodes, ne_a = n_edges, nbf_a = nbf, ch_a = chunk;
            void* args[] = {&row_a, &col_a, &bt_a, &bs_a, &eb_a, &dis_a,
                            &nn_a, &ne_a, &nbf_a, &ch_a};
            hipLaunchCooperativeKernel((const void*)kBuild, dim3(GB), dim3(256),
                                       args, 0, stream);
        } else {
            kP1_ticket<<<GB, 256, 0, stream>>>(col, BinTotal, tickets, n_edges,
                                               nbf, chunk);
            kP2_scan<<<1, 256, 0, stream>>>(BinTotal, BucketStart, nbf, n_edges);
            kP3_scatter<<<GB, 256, 0, stream>>>(row, col, BucketStart, tickets,
                                                EdgeBuf, n_edges, nbf, chunk);
            kP4_degree<<<nbf, 256, 0, stream>>>(EdgeBuf, BucketStart, dis, n_nodes);
        }
        int ntiles = (n_nodes + 15) / 16;
        int mm_blocks = (ntiles + 3) / 4;
        k_matmul_mfma<<<mm_blocks, 256, 0, stream>>>(x, W, dis, h, n_nodes);
        kF_sortagg<<<nbf, 512, 0, stream>>>(EdgeBuf, BucketStart, dis, h, b,
                                            out, spill, spillcur, n_nodes);
    } else {
        // ---- last-resort fallback: atomic scatter, fp32 h ----
        char* p = (char*)d_ws;
        int* deg_f = (int*)p;
        float* dis_f = (float*)(p + align_up((size_t)n_nodes * 4, 256));
        float* h_f = (float*)(p + 2 * align_up((size_t)n_nodes * 4, 256));
        hipMemsetAsync(deg_f, 0, (size_t)n_nodes * 4, stream);
        hipMemsetAsync(out, 0, (size_t)out_size * 4, stream);
        k_degree_fb<<<1024, 256, 0, stream>>>(col, deg_f, n_edges);
        k_rsqrt_fb<<<(n_nodes + 255) / 256, 256, 0, stream>>>(deg_f, dis_f, n_nodes);
        k_matmul_f32<<<1024, 256, 0, stream>>>(x, W, dis_f, h_f, n_nodes);
        k_scatter_fb<<<2048, 256, 0, stream>>>(row, col, dis_f, h_f, out, n_edges);
        k_bias_relu_fb<<<2048, 256, 0, stream>>>(out, b, n_nodes * OUT_DIM);
    }
}

// Round 13
// 241.947 us; speedup vs baseline: 1.1001x; 1.1001x over previous
//
#include <hip/hip_runtime.h>
#include <hip/hip_bf16.h>

#define IN_DIM 128
#define OUT_DIM 64
#define FLOG 7                     // fine bucket: 128 nodes
#define FNPB (1 << FLOG)
#define MAXFINE 1024               // fine bins supported (n_nodes <= 128K)
#define BB 512                     // build grid blocks
#define BT 512                     // build threads/block (8 waves, 2 blk/CU)
#define CAP 4096                   // LDS sorted-edge capacity per fine bucket

static inline size_t align_up(size_t v, size_t a) { return (v + a - 1) & ~(a - 1); }

__device__ __forceinline__ unsigned short f2bf(float f) {
    unsigned int x = __float_as_uint(f);
    unsigned int r = (x + 0x7fffu + ((x >> 16) & 1u)) >> 16;  // RTNE
    return (unsigned short)r;
}

typedef _Float16 half8 __attribute__((ext_vector_type(8)));
typedef float f32x4 __attribute__((ext_vector_type(4)));

// ---------------------------------------------------------------------------
// kA: per-block LDS fine histogram + global ticket atomics + fused per-node
// degree (global int atomic, no return, shares the col load).
// ---------------------------------------------------------------------------
__global__ void __launch_bounds__(BT) kA_ticket(
    const int* __restrict__ col, int* __restrict__ BinTotal,
    int* __restrict__ deg, int* __restrict__ tickets,
    int n_edges, int nbf, int chunk) {
    __shared__ int hist[MAXFINE];
    int t = threadIdx.x;
    for (int i = t; i < nbf; i += BT) hist[i] = 0;
    __syncthreads();
    int start = blockIdx.x * chunk;
    int end = min(n_edges, start + chunk);
    for (int i = start + t; i < end; i += BT) {
        int c = col[i];
        atomicAdd(&hist[c >> FLOG], 1);
        atomicAdd(&deg[c], 1);          // fire-and-forget; kD deleted
    }
    __syncthreads();
    int* trow = tickets + (size_t)blockIdx.x * nbf;
    for (int i = t; i < nbf; i += BT)
        trow[i] = atomicAdd(&BinTotal[i], hist[i]);
}

// ---------------------------------------------------------------------------
// kS2: exclusive scan of BinTotal -> BucketStart[nbf+1] (single block)
// ---------------------------------------------------------------------------
__global__ void __launch_bounds__(256) kS2_scantotals(
    const int* __restrict__ BinTotal, int* __restrict__ BucketStart,
    int nbf, int n_edges) {
    __shared__ int s[256];
    int t = threadIdx.x;
    int v[4];
#pragma unroll
    for (int j = 0; j < 4; ++j) {
        int idx = t * 4 + j;
        v[j] = (idx < nbf) ? BinTotal[idx] : 0;
    }
    int tsum = v[0] + v[1] + v[2] + v[3];
    s[t] = tsum;
    __syncthreads();
    for (int off = 1; off < 256; off <<= 1) {
        int x = (t >= off) ? s[t - off] : 0;
        __syncthreads();
        s[t] += x;
        __syncthreads();
    }
    int run = s[t] - tsum;
#pragma unroll
    for (int j = 0; j < 4; ++j) {
        int idx = t * 4 + j;
        if (idx < nbf) BucketStart[idx] = run;
        run += v[j];
    }
    if (t == 0) BucketStart[nbf] = n_edges;
}

// ---------------------------------------------------------------------------
// kB: scatter edges to fine bucket regions, packed (row<<7)|(col&127).
// LDS cursors seeded from BucketStart + tickets.
// ---------------------------------------------------------------------------
__global__ void __launch_bounds__(BT) kB_scatter(
    const int* __restrict__ row, const int* __restrict__ col,
    const int* __restrict__ BucketStart, const int* __restrict__ tickets,
    unsigned int* __restrict__ EdgeBuf, int n_edges, int nbf, int chunk) {
    __shared__ int cur[MAXFINE];
    const int* trow = tickets + (size_t)blockIdx.x * nbf;
    int t = threadIdx.x;
    for (int i = t; i < nbf; i += BT)
        cur[i] = BucketStart[i] + trow[i];
    __syncthreads();
    int start = blockIdx.x * chunk;
    int end = min(n_edges, start + chunk);
    for (int i = start + t; i < end; i += BT) {
        int c = col[i];
        int r = row[i];
        int p = atomicAdd(&cur[c >> FLOG], 1);
        EdgeBuf[p] = ((unsigned int)r << FLOG) | (unsigned int)(c & (FNPB - 1));
    }
}

// ---------------------------------------------------------------------------
// k_matmul_mfma: h(bf16) = (x @ W) * rsqrt(deg) via f16 MFMA 16x16x32.
// One wave per 16-node tile; W fragments hoisted; no LDS/barriers.
// dis computed inline from the int degree array (kD deleted).
// ---------------------------------------------------------------------------
__global__ void __launch_bounds__(256) k_matmul_mfma(
    const float* __restrict__ x, const float* __restrict__ W,
    const int* __restrict__ deg, unsigned short* __restrict__ h, int n_nodes) {
    const int lane = threadIdx.x & 63;
    const int m = lane & 15;
    const int q = lane >> 4;
    const int wid = (blockIdx.x * blockDim.x + threadIdx.x) >> 6;
    const int ntiles = (n_nodes + 15) >> 4;
    if (wid >= ntiles) return;

    half8 bfrag[4][4];
#pragma unroll
    for (int kt = 0; kt < 4; ++kt) {
#pragma unroll
        for (int nt = 0; nt < 4; ++nt) {
            int k0 = kt * 32 + q * 8;
            int c = nt * 16 + m;
#pragma unroll
            for (int j = 0; j < 8; ++j)
                bfrag[kt][nt][j] = (_Float16)W[(size_t)(k0 + j) * OUT_DIM + c];
        }
    }

    const int nb = wid << 4;
    int arow = nb + m;
    if (arow >= n_nodes) arow = n_nodes - 1;
    const float* xr = x + (size_t)arow * IN_DIM;

    f32x4 acc[4];
#pragma unroll
    for (int nt = 0; nt < 4; ++nt) acc[nt] = (f32x4){0.f, 0.f, 0.f, 0.f};

#pragma unroll
    for (int kt = 0; kt < 4; ++kt) {
        const float4* xp = (const float4*)(xr + kt * 32 + q * 8);
        float4 lo = xp[0];
        float4 hi = xp[1];
        half8 afrag;
        afrag[0] = (_Float16)lo.x; afrag[1] = (_Float16)lo.y;
        afrag[2] = (_Float16)lo.z; afrag[3] = (_Float16)lo.w;
        afrag[4] = (_Float16)hi.x; afrag[5] = (_Float16)hi.y;
        afrag[6] = (_Float16)hi.z; afrag[7] = (_Float16)hi.w;
#pragma unroll
        for (int nt = 0; nt < 4; ++nt)
            acc[nt] = __builtin_amdgcn_mfma_f32_16x16x32_f16(afrag, bfrag[kt][nt],
                                                             acc[nt], 0, 0, 0);
    }

#pragma unroll
    for (int r = 0; r < 4; ++r) {
        int node = nb + q * 4 + r;
        if (node < n_nodes) {
            int d = deg[node];
            float dv = (d > 0) ? rsqrtf((float)d) : 0.0f;
            unsigned short* hp = h + (size_t)node * OUT_DIM + m;
#pragma unroll
            for (int nt = 0; nt < 4; ++nt)
                hp[nt * 16] = f2bf(acc[nt][r] * dv);
        }
    }
}

// ---------------------------------------------------------------------------
// kF: fused per-fine-bucket local sort (into LDS) + gather-aggregate.
// Round-10 proven form. cnt[nl] IS the node degree -> dis computed inline.
// Int LDS atomics only (round 9: fp32 LDS atomics = 15x loss).
// ---------------------------------------------------------------------------
__global__ void __launch_bounds__(512) kF_sortagg(
    const unsigned int* __restrict__ EdgeBuf, const int* __restrict__ BucketStart,
    const unsigned short* __restrict__ h, const float* __restrict__ b,
    float* __restrict__ out, int* __restrict__ spill, int* __restrict__ spillcur,
    int n_nodes) {
    __shared__ int cnt[FNPB];
    __shared__ int seg[FNPB];
    __shared__ int cursor[FNPB];
    __shared__ int sbuf[CAP];
    __shared__ int sbase_sh;
    int t = threadIdx.x;
    int es = BucketStart[blockIdx.x];
    int ee = BucketStart[blockIdx.x + 1];
    int ne = ee - es;
    int nb0 = blockIdx.x << FLOG;

    if (t < FNPB) cnt[t] = 0;
    __syncthreads();
    for (int i = es + t; i < ee; i += 512)
        atomicAdd(&cnt[EdgeBuf[i] & (FNPB - 1)], 1);
    __syncthreads();

    if (t < FNPB) seg[t] = cnt[t];
    __syncthreads();
    for (int off = 1; off < FNPB; off <<= 1) {
        int x = 0;
        if (t < FNPB && t >= off) x = seg[t - off];
        __syncthreads();
        if (t < FNPB) seg[t] += x;
        __syncthreads();
    }
    if (t < FNPB) cursor[t] = seg[t] - cnt[t];
    __syncthreads();

    if (t == 0 && ne > CAP) sbase_sh = atomicAdd(spillcur, ne);
    __syncthreads();

    const int lane = t & 63;
    const int wv = t >> 6;
    const int quarter = lane >> 4;
    const int qlane = lane & 15;
    float4 bias = ((const float4*)b)[qlane];

    if (ne <= CAP) {
        for (int i = es + t; i < ee; i += 512) {
            unsigned int v = EdgeBuf[i];
            int p = atomicAdd(&cursor[v & (FNPB - 1)], 1);
            sbuf[p] = (int)(v >> FLOG);
        }
        __syncthreads();

        for (int nl = wv; nl < FNPB; nl += 8) {
            int node = nb0 + nl;
            if (node >= n_nodes) break;
            int e_ = seg[nl];
            int dcount = cnt[nl];
            int s_ = e_ - dcount;
            float a0 = 0.f, a1 = 0.f, a2 = 0.f, a3 = 0.f;
            for (int j0 = s_; j0 < e_; j0 += 8) {
                int iA = j0 + quarter;
                int iB = j0 + quarter + 4;
                int rA = sbuf[iA < e_ ? iA : s_];
                int rB = sbuf[iB < e_ ? iB : s_];
                uint2 vA = make_uint2(0u, 0u), vB = make_uint2(0u, 0u);
                if (iA < e_)
                    vA = *(const uint2*)(h + (size_t)rA * OUT_DIM + qlane * 4);
                if (iB < e_)
                    vB = *(const uint2*)(h + (size_t)rB * OUT_DIM + qlane * 4);
                a0 += __uint_as_float(vA.x << 16);
                a1 += __uint_as_float(vA.x & 0xFFFF0000u);
                a2 += __uint_as_float(vA.y << 16);
                a3 += __uint_as_float(vA.y & 0xFFFF0000u);
                a0 += __uint_as_float(vB.x << 16);
                a1 += __uint_as_float(vB.x & 0xFFFF0000u);
                a2 += __uint_as_float(vB.y << 16);
                a3 += __uint_as_float(vB.y & 0xFFFF0000u);
            }
            a0 += __shfl_xor(a0, 16, 64); a0 += __shfl_xor(a0, 32, 64);
            a1 += __shfl_xor(a1, 16, 64); a1 += __shfl_xor(a1, 32, 64);
            a2 += __shfl_xor(a2, 16, 64); a2 += __shfl_xor(a2, 32, 64);
            a3 += __shfl_xor(a3, 16, 64); a3 += __shfl_xor(a3, 32, 64);
            if (quarter == 0) {
                float dv = (dcount > 0) ? rsqrtf((float)dcount) : 0.0f;
                float4 o;
                o.x = fmaxf(fmaf(a0, dv, bias.x), 0.f);
                o.y = fmaxf(fmaf(a1, dv, bias.y), 0.f);
                o.z = fmaxf(fmaf(a2, dv, bias.z), 0.f);
                o.w = fmaxf(fmaf(a3, dv, bias.w), 0.f);
                ((float4*)(out + (size_t)node * OUT_DIM))[qlane] = o;
            }
        }
    } else {
        int sbase = sbase_sh;
        for (int i = es + t; i < ee; i += 512) {
            unsigned int v = EdgeBuf[i];
            int p = atomicAdd(&cursor[v & (FNPB - 1)], 1);
            spill[sbase + p] = (int)(v >> FLOG);
        }
        __threadfence();
        __syncthreads();
        for (int nl = wv; nl < FNPB; nl += 8) {
            int node = nb0 + nl;
            if (node >= n_nodes) break;
            int e_ = seg[nl];
            int dcount = cnt[nl];
            int s_ = e_ - dcount;
            float a0 = 0.f, a1 = 0.f, a2 = 0.f, a3 = 0.f;
            for (int j0 = s_; j0 < e_; j0 += 8) {
                int iA = j0 + quarter;
                int iB = j0 + quarter + 4;
                int rA = spill[sbase + (iA < e_ ? iA : s_)];
                int rB = spill[sbase + (iB < e_ ? iB : s_)];
                uint2 vA = make_uint2(0u, 0u), vB = make_uint2(0u, 0u);
                if (iA < e_)
                    vA = *(const uint2*)(h + (size_t)rA * OUT_DIM + qlane * 4);
                if (iB < e_)
                    vB = *(const uint2*)(h + (size_t)rB * OUT_DIM + qlane * 4);
                a0 += __uint_as_float(vA.x << 16);
                a1 += __uint_as_float(vA.x & 0xFFFF0000u);
                a2 += __uint_as_float(vA.y << 16);
                a3 += __uint_as_float(vA.y & 0xFFFF0000u);
                a0 += __uint_as_float(vB.x << 16);
                a1 += __uint_as_float(vB.x & 0xFFFF0000u);
                a2 += __uint_as_float(vB.y << 16);
                a3 += __uint_as_float(vB.y & 0xFFFF0000u);
            }
            a0 += __shfl_xor(a0, 16, 64); a0 += __shfl_xor(a0, 32, 64);
            a1 += __shfl_xor(a1, 16, 64); a1 += __shfl_xor(a1, 32, 64);
            a2 += __shfl_xor(a2, 16, 64); a2 += __shfl_xor(a2, 32, 64);
            a3 += __shfl_xor(a3, 16, 64); a3 += __shfl_xor(a3, 32, 64);
            if (quarter == 0) {
                float dv = (dcount > 0) ? rsqrtf((float)dcount) : 0.0f;
                float4 o;
                o.x = fmaxf(fmaf(a0, dv, bias.x), 0.f);
                o.y = fmaxf(fmaf(a1, dv, bias.y), 0.f);
                o.z = fmaxf(fmaf(a2, dv, bias.z), 0.f);
                o.w = fmaxf(fmaf(a3, dv, bias.w), 0.f);
                ((float4*)(out + (size_t)node * OUT_DIM))[qlane] = o;
            }
        }
    }
}

// ---------------------------------------------------------------------------
// Last-resort fallback (exotic sizes): atomic scatter, fp32 h
// ---------------------------------------------------------------------------
#define MM_NODES 16
__global__ void __launch_bounds__(256) k_matmul_f32(
    const float* __restrict__ x, const float* __restrict__ W,
    const float* __restrict__ dis, float* __restrict__ h, int n_nodes) {
    __shared__ float xs[MM_NODES * IN_DIM];
    const int lane = threadIdx.x & 63;
    const int wv = threadIdx.x >> 6;
    float w[IN_DIM];
#pragma unroll
    for (int k = 0; k < IN_DIM; ++k) w[k] = W[k * OUT_DIM + lane];
    int nchunks = (n_nodes + MM_NODES - 1) / MM_NODES;
    for (int ch = blockIdx.x; ch < nchunks; ch += gridDim.x) {
        int base = ch * MM_NODES;
        int nrows = min(MM_NODES, n_nodes - base);
        __syncthreads();
        const float4* xg = (const float4*)(x + (size_t)base * IN_DIM);
        int nf4 = nrows * IN_DIM / 4;
        for (int i = threadIdx.x; i < nf4; i += 256) ((float4*)xs)[i] = xg[i];
        __syncthreads();
#pragma unroll
        for (int j = 0; j < 4; ++j) {
            int local = wv * 4 + j;
            int node = base + local;
            if (local < nrows) {
                const float4* xr = (const float4*)(xs + local * IN_DIM);
                float acc = 0.0f;
#pragma unroll
                for (int k4 = 0; k4 < IN_DIM / 4; ++k4) {
                    float4 xv = xr[k4];
                    acc = fmaf(xv.x, w[k4 * 4 + 0], acc);
                    acc = fmaf(xv.y, w[k4 * 4 + 1], acc);
                    acc = fmaf(xv.z, w[k4 * 4 + 2], acc);
                    acc = fmaf(xv.w, w[k4 * 4 + 3], acc);
                }
                h[(size_t)node * OUT_DIM + lane] = acc * dis[node];
            }
        }
    }
}

__global__ void k_degree_fb(const int* __restrict__ col, int* __restrict__ deg,
                            int n_edges) {
    int i = blockIdx.x * blockDim.x + threadIdx.x;
    int stride = gridDim.x * blockDim.x;
    for (; i < n_edges; i += stride) atomicAdd(&deg[col[i]], 1);
}

__global__ void k_rsqrt_fb(const int* __restrict__ deg, float* __restrict__ dis, int n) {
    int i = blockIdx.x * blockDim.x + threadIdx.x;
    if (i < n) {
        int d = deg[i];
        dis[i] = (d > 0) ? rsqrtf((float)d) : 0.0f;
    }
}

__global__ void __launch_bounds__(256) k_scatter_fb(
    const int* __restrict__ row, const int* __restrict__ col,
    const float* __restrict__ dis, const float* __restrict__ h,
    float* __restrict__ out, int n_edges) {
    const int lane = threadIdx.x & 63;
    int e = (blockIdx.x * blockDim.x + threadIdx.x) >> 6;
    int nw = (gridDim.x * blockDim.x) >> 6;
    for (; e < n_edges; e += nw) {
        int r = row[e];
        int c = col[e];
        float v = h[(size_t)r * OUT_DIM + lane] * dis[c];
        atomicAdd(&out[(size_t)c * OUT_DIM + lane], v);
    }
}

__global__ void k_bias_relu_fb(float* __restrict__ out, const float* __restrict__ b,
                               int total) {
    int i = blockIdx.x * blockDim.x + threadIdx.x;
    int stride = gridDim.x * blockDim.x;
    for (; i < total; i += stride) {
        float v = out[i] + b[i & (OUT_DIM - 1)];
        out[i] = fmaxf(v, 0.0f);
    }
}

extern "C" void kernel_launch(void* const* d_in, const int* in_sizes, int n_in,
                              void* d_out, int out_size, void* d_ws, size_t ws_size,
                              hipStream_t stream) {
    const float* x = (const float*)d_in[0];
    const int* ei = (const int*)d_in[1];  // [2, E] int32
    const float* W = (const float*)d_in[2];
    const float* b = (const float*)d_in[3];
    float* out = (float*)d_out;

    const int n_nodes = in_sizes[0] / IN_DIM;
    const int n_edges = in_sizes[1] / 2;
    const int* row = ei;
    const int* col = ei + n_edges;

    const int nbf = (n_nodes + FNPB - 1) >> FLOG;   // fine buckets
    const int chunk = (n_edges + BB - 1) / BB;

    // ---- workspace layout (BinTotal..deg contiguous for one memset) ----
    char* wsb = (char*)d_ws;
    size_t off = 0;
    int* BinTotal = (int*)(wsb + off);   off += (size_t)(nbf + 8) * 4;
    int* spillcur = BinTotal + nbf;
    int* deg = (int*)(wsb + off);        off += (size_t)n_nodes * 4;
    const size_t zero_bytes = off;       // memset covers BinTotal+spillcur+deg
    off = align_up(off, 256);
    int* BucketStart = (int*)(wsb + off);off += align_up((size_t)(nbf + 1) * 4, 256);
    int* tickets = (int*)(wsb + off);    off += align_up((size_t)BB * nbf * 4, 256);
    unsigned int* EdgeBuf = (unsigned int*)(wsb + off);
                                         off += align_up((size_t)n_edges * 4, 256);
    int* spill = (int*)(wsb + off);      off += align_up((size_t)n_edges * 4, 256);
    unsigned short* h = (unsigned short*)(wsb + off);
                                         off += (size_t)n_nodes * OUT_DIM * 2;
    const size_t needed = off;

    const bool ok = (ws_size >= needed) && (nbf <= MAXFINE) &&
                    (n_nodes <= (1 << 24));  // row fits in 32-7=25 bits

    if (ok) {
        hipMemsetAsync(BinTotal, 0, zero_bytes, stream);
        kA_ticket<<<BB, BT, 0, stream>>>(col, BinTotal, deg, tickets, n_edges,
                                         nbf, chunk);
        kS2_scantotals<<<1, 256, 0, stream>>>(BinTotal, BucketStart, nbf, n_edges);
        kB_scatter<<<BB, BT, 0, stream>>>(row, col, BucketStart, tickets, EdgeBuf,
                                          n_edges, nbf, chunk);
        int ntiles = (n_nodes + 15) / 16;
        int mm_blocks = (ntiles + 3) / 4;
        k_matmul_mfma<<<mm_blocks, 256, 0, stream>>>(x, W, deg, h, n_nodes);
        kF_sortagg<<<nbf, 512, 0, stream>>>(EdgeBuf, BucketStart, h, b, out,
                                            spill, spillcur, n_nodes);
    } else {
        // ---- last-resort fallback: atomic scatter, fp32 h ----
        char* p = (char*)d_ws;
        int* deg_f = (int*)p;
        float* dis_f = (float*)(p + align_up((size_t)n_nodes * 4, 256));
        float* h_f = (float*)(p + 2 * align_up((size_t)n_nodes * 4, 256));
        hipMemsetAsync(deg_f, 0, (size_t)n_nodes * 4, stream);
        hipMemsetAsync(out, 0, (size_t)out_size * 4, stream);
        k_degree_fb<<<1024, 256, 0, stream>>>(col, deg_f, n_edges);
        k_rsqrt_fb<<<(n_nodes + 255) / 256, 256, 0, stream>>>(deg_f, dis_f, n_nodes);
        k_matmul_f32<<<1024, 256, 0, stream>>>(x, W, dis_f, h_f, n_nodes);
        k_scatter_fb<<<2048, 256, 0, stream>>>(row, col, dis_f, h_f, out, n_edges);
        k_bias_relu_fb<<<2048, 256, 0, stream>>>(out, b, n_nodes * OUT_DIM);
    }
}

// Round 14
// 181.009 us; speedup vs baseline: 1.4704x; 1.3367x over previous
//
#include <hip/hip_runtime.h>
#include <hip/hip_bf16.h>

#define IN_DIM 128
#define OUT_DIM 64
#define FLOG 7                     // fine bucket: 128 nodes
#define FNPB (1 << FLOG)
#define MAXFINE 1024               // fine bins supported (n_nodes <= 128K)
#define BB 512                     // build grid blocks
#define BT 512                     // build threads/block
#define EBUF_MAX 4096              // max edges per build block (LDS staging)
#define CAP 4096                   // slot capacity per fine bucket (45 sigma)
#define SPILL_MAX 65536            // slot-overflow spill list capacity

static inline size_t align_up(size_t v, size_t a) { return (v + a - 1) & ~(a - 1); }

__device__ __forceinline__ unsigned short f2bf(float f) {
    unsigned int x = __float_as_uint(f);
    unsigned int r = (x + 0x7fffu + ((x >> 16) & 1u)) >> 16;  // RTNE
    return (unsigned short)r;
}

typedef _Float16 half8 __attribute__((ext_vector_type(8)));
typedef float f32x4 __attribute__((ext_vector_type(4)));

// ---------------------------------------------------------------------------
// kAB: single-pass slotted build. Stage chunk in LDS -> LDS histogram ->
// one global atomic per (block,bin) reserves a range in the bucket's slot ->
// scatter from LDS. No scan, no tickets, no second col pass.
// Overflow (>CAP, ~45 sigma for this input) goes to a global spill list.
// ---------------------------------------------------------------------------
__global__ void __launch_bounds__(BT) kAB_build(
    const int* __restrict__ row, const int* __restrict__ col,
    int* __restrict__ BinSize, unsigned int* __restrict__ EdgeBuf,
    uint2* __restrict__ spill, int* __restrict__ spillcur,
    int n_edges, int nbf, int chunk) {
    __shared__ int er[EBUF_MAX];    // 16 KB
    __shared__ int ec[EBUF_MAX];    // 16 KB
    __shared__ int hist[MAXFINE];   // 4 KB: counts -> reserved base/cursor
    int t = threadIdx.x;
    int start = blockIdx.x * chunk;
    int end = min(n_edges, start + chunk);
    int n = end - start;

    for (int i = t; i < nbf; i += BT) hist[i] = 0;
    __syncthreads();
    for (int i = t; i < n; i += BT) {           // coalesced single read
        int r = row[start + i];
        int c = col[start + i];
        er[i] = r;
        ec[i] = c;
        atomicAdd(&hist[c >> FLOG], 1);
    }
    __syncthreads();
    for (int i = t; i < nbf; i += BT) {         // reserve slot ranges
        int cv = hist[i];
        hist[i] = cv ? atomicAdd(&BinSize[i], cv) : 0;
    }
    __syncthreads();
    for (int i = t; i < n; i += BT) {           // scatter from LDS
        int c = ec[i];
        int bin = c >> FLOG;
        int pos = atomicAdd(&hist[bin], 1);
        if (pos < CAP) {
            EdgeBuf[(size_t)bin * CAP + pos] =
                ((unsigned int)er[i] << FLOG) | (unsigned int)(c & (FNPB - 1));
        } else {
            int sp = atomicAdd(spillcur, 1);
            if (sp < SPILL_MAX)
                spill[sp] = make_uint2((unsigned int)er[i], (unsigned int)c);
        }
    }
}

// ---------------------------------------------------------------------------
// kD: per-bucket degree histogram from slots (+spill filter) -> dis.
// Feeds only the matmul; kF recomputes cnt itself.
// ---------------------------------------------------------------------------
__global__ void __launch_bounds__(256) kD_degree(
    const unsigned int* __restrict__ EdgeBuf, const int* __restrict__ BinSize,
    const uint2* __restrict__ spill, const int* __restrict__ spillcur,
    float* __restrict__ dis, int n_nodes) {
    __shared__ int cnt[FNPB];
    int t = threadIdx.x;
    int b = blockIdx.x;
    if (t < FNPB) cnt[t] = 0;
    __syncthreads();
    int sz = min(BinSize[b], CAP);
    const unsigned int* slot = EdgeBuf + (size_t)b * CAP;
    for (int i = t; i < sz; i += 256)
        atomicAdd(&cnt[slot[i] & (FNPB - 1)], 1);
    int sn = min(*spillcur, SPILL_MAX);          // usually 0
    for (int i = t; i < sn; i += 256) {
        uint2 e = spill[i];
        if ((int)(e.y >> FLOG) == b) atomicAdd(&cnt[e.y & (FNPB - 1)], 1);
    }
    __syncthreads();
    int node = (b << FLOG) + t;
    if (t < FNPB && node < n_nodes) {
        int d = cnt[t];
        dis[node] = (d > 0) ? rsqrtf((float)d) : 0.0f;
    }
}

// ---------------------------------------------------------------------------
// k_matmul_mfma: h(bf16) = (x @ W) * dis via f16 MFMA 16x16x32.
// One wave per 16-node tile; W fragments hoisted; no LDS/barriers.
// ---------------------------------------------------------------------------
__global__ void __launch_bounds__(256) k_matmul_mfma(
    const float* __restrict__ x, const float* __restrict__ W,
    const float* __restrict__ dis, unsigned short* __restrict__ h, int n_nodes) {
    const int lane = threadIdx.x & 63;
    const int m = lane & 15;
    const int q = lane >> 4;
    const int wid = (blockIdx.x * blockDim.x + threadIdx.x) >> 6;
    const int ntiles = (n_nodes + 15) >> 4;
    if (wid >= ntiles) return;

    half8 bfrag[4][4];
#pragma unroll
    for (int kt = 0; kt < 4; ++kt) {
#pragma unroll
        for (int nt = 0; nt < 4; ++nt) {
            int k0 = kt * 32 + q * 8;
            int c = nt * 16 + m;
#pragma unroll
            for (int j = 0; j < 8; ++j)
                bfrag[kt][nt][j] = (_Float16)W[(size_t)(k0 + j) * OUT_DIM + c];
        }
    }

    const int nb = wid << 4;
    int arow = nb + m;
    if (arow >= n_nodes) arow = n_nodes - 1;
    const float* xr = x + (size_t)arow * IN_DIM;

    f32x4 acc[4];
#pragma unroll
    for (int nt = 0; nt < 4; ++nt) acc[nt] = (f32x4){0.f, 0.f, 0.f, 0.f};

#pragma unroll
    for (int kt = 0; kt < 4; ++kt) {
        const float4* xp = (const float4*)(xr + kt * 32 + q * 8);
        float4 lo = xp[0];
        float4 hi = xp[1];
        half8 afrag;
        afrag[0] = (_Float16)lo.x; afrag[1] = (_Float16)lo.y;
        afrag[2] = (_Float16)lo.z; afrag[3] = (_Float16)lo.w;
        afrag[4] = (_Float16)hi.x; afrag[5] = (_Float16)hi.y;
        afrag[6] = (_Float16)hi.z; afrag[7] = (_Float16)hi.w;
#pragma unroll
        for (int nt = 0; nt < 4; ++nt)
            acc[nt] = __builtin_amdgcn_mfma_f32_16x16x32_f16(afrag, bfrag[kt][nt],
                                                             acc[nt], 0, 0, 0);
    }

#pragma unroll
    for (int r = 0; r < 4; ++r) {
        int node = nb + q * 4 + r;
        if (node < n_nodes) {
            float dv = dis[node];
            unsigned short* hp = h + (size_t)node * OUT_DIM + m;
#pragma unroll
            for (int nt = 0; nt < 4; ++nt)
                hp[nt * 16] = f2bf(acc[nt][r] * dv);
        }
    }
}

// ---------------------------------------------------------------------------
// kF: fused per-bucket local sort (into LDS) + gather-aggregate, reading the
// bucket's slot (+spill filter). dis computed inline from cnt. Int LDS
// atomics only (round 9: fp32 LDS atomics = 15x loss).
// ---------------------------------------------------------------------------
__global__ void __launch_bounds__(512) kF_sortagg(
    const unsigned int* __restrict__ EdgeBuf, const int* __restrict__ BinSize,
    const uint2* __restrict__ spill, const int* __restrict__ spillcur,
    const unsigned short* __restrict__ h, const float* __restrict__ b,
    float* __restrict__ out, int* __restrict__ arena, int* __restrict__ arenacur,
    int n_nodes) {
    __shared__ int cnt[FNPB];
    __shared__ int seg[FNPB];
    __shared__ int cursor[FNPB];
    __shared__ int sbuf[CAP];
    __shared__ int abase_sh;
    int t = threadIdx.x;
    int bk = blockIdx.x;
    int nb0 = bk << FLOG;
    int sz = min(BinSize[bk], CAP);
    const unsigned int* slot = EdgeBuf + (size_t)bk * CAP;
    int sn = min(*spillcur, SPILL_MAX);          // usually 0

    if (t < FNPB) cnt[t] = 0;
    __syncthreads();
    for (int i = t; i < sz; i += 512)
        atomicAdd(&cnt[slot[i] & (FNPB - 1)], 1);
    for (int i = t; i < sn; i += 512) {
        uint2 e = spill[i];
        if ((int)(e.y >> FLOG) == bk) atomicAdd(&cnt[e.y & (FNPB - 1)], 1);
    }
    __syncthreads();

    if (t < FNPB) seg[t] = cnt[t];
    __syncthreads();
    for (int off = 1; off < FNPB; off <<= 1) {
        int x = 0;
        if (t < FNPB && t >= off) x = seg[t - off];
        __syncthreads();
        if (t < FNPB) seg[t] += x;
        __syncthreads();
    }
    if (t < FNPB) cursor[t] = seg[t] - cnt[t];
    __syncthreads();

    int ne = seg[FNPB - 1];
    if (t == 0 && ne > CAP) abase_sh = atomicAdd(arenacur, ne);
    __syncthreads();

    const int lane = t & 63;
    const int wv = t >> 6;
    const int quarter = lane >> 4;
    const int qlane = lane & 15;
    float4 bias = ((const float4*)b)[qlane];

    if (ne <= CAP) {
        for (int i = t; i < sz; i += 512) {
            unsigned int v = slot[i];
            int p = atomicAdd(&cursor[v & (FNPB - 1)], 1);
            sbuf[p] = (int)(v >> FLOG);
        }
        for (int i = t; i < sn; i += 512) {
            uint2 e = spill[i];
            if ((int)(e.y >> FLOG) == bk) {
                int p = atomicAdd(&cursor[e.y & (FNPB - 1)], 1);
                sbuf[p] = (int)e.x;
            }
        }
        __syncthreads();

        for (int nl = wv; nl < FNPB; nl += 8) {
            int node = nb0 + nl;
            if (node >= n_nodes) break;
            int e_ = seg[nl];
            int dcount = cnt[nl];
            int s_ = e_ - dcount;
            float a0 = 0.f, a1 = 0.f, a2 = 0.f, a3 = 0.f;
            for (int j0 = s_; j0 < e_; j0 += 8) {
                int iA = j0 + quarter;
                int iB = j0 + quarter + 4;
                int rA = sbuf[iA < e_ ? iA : s_];
                int rB = sbuf[iB < e_ ? iB : s_];
                uint2 vA = make_uint2(0u, 0u), vB = make_uint2(0u, 0u);
                if (iA < e_)
                    vA = *(const uint2*)(h + (size_t)rA * OUT_DIM + qlane * 4);
                if (iB < e_)
                    vB = *(const uint2*)(h + (size_t)rB * OUT_DIM + qlane * 4);
                a0 += __uint_as_float(vA.x << 16);
                a1 += __uint_as_float(vA.x & 0xFFFF0000u);
                a2 += __uint_as_float(vA.y << 16);
                a3 += __uint_as_float(vA.y & 0xFFFF0000u);
                a0 += __uint_as_float(vB.x << 16);
                a1 += __uint_as_float(vB.x & 0xFFFF0000u);
                a2 += __uint_as_float(vB.y << 16);
                a3 += __uint_as_float(vB.y & 0xFFFF0000u);
            }
            a0 += __shfl_xor(a0, 16, 64); a0 += __shfl_xor(a0, 32, 64);
            a1 += __shfl_xor(a1, 16, 64); a1 += __shfl_xor(a1, 32, 64);
            a2 += __shfl_xor(a2, 16, 64); a2 += __shfl_xor(a2, 32, 64);
            a3 += __shfl_xor(a3, 16, 64); a3 += __shfl_xor(a3, 32, 64);
            if (quarter == 0) {
                float dv = (dcount > 0) ? rsqrtf((float)dcount) : 0.0f;
                float4 o;
                o.x = fmaxf(fmaf(a0, dv, bias.x), 0.f);
                o.y = fmaxf(fmaf(a1, dv, bias.y), 0.f);
                o.z = fmaxf(fmaf(a2, dv, bias.z), 0.f);
                o.w = fmaxf(fmaf(a3, dv, bias.w), 0.f);
                ((float4*)(out + (size_t)node * OUT_DIM))[qlane] = o;
            }
        }
    } else {
        // impossible-size bucket: sort into a global arena slice
        int abase = abase_sh;
        for (int i = t; i < sz; i += 512) {
            unsigned int v = slot[i];
            int p = atomicAdd(&cursor[v & (FNPB - 1)], 1);
            arena[abase + p] = (int)(v >> FLOG);
        }
        for (int i = t; i < sn; i += 512) {
            uint2 e = spill[i];
            if ((int)(e.y >> FLOG) == bk) {
                int p = atomicAdd(&cursor[e.y & (FNPB - 1)], 1);
                arena[abase + p] = (int)e.x;
            }
        }
        __threadfence();
        __syncthreads();
        for (int nl = wv; nl < FNPB; nl += 8) {
            int node = nb0 + nl;
            if (node >= n_nodes) break;
            int e_ = seg[nl];
            int dcount = cnt[nl];
            int s_ = e_ - dcount;
            float a0 = 0.f, a1 = 0.f, a2 = 0.f, a3 = 0.f;
            for (int j0 = s_; j0 < e_; j0 += 8) {
                int iA = j0 + quarter;
                int iB = j0 + quarter + 4;
                int rA = arena[abase + (iA < e_ ? iA : s_)];
                int rB = arena[abase + (iB < e_ ? iB : s_)];
                uint2 vA = make_uint2(0u, 0u), vB = make_uint2(0u, 0u);
                if (iA < e_)
                    vA = *(const uint2*)(h + (size_t)rA * OUT_DIM + qlane * 4);
                if (iB < e_)
                    vB = *(const uint2*)(h + (size_t)rB * OUT_DIM + qlane * 4);
                a0 += __uint_as_float(vA.x << 16);
                a1 += __uint_as_float(vA.x & 0xFFFF0000u);
                a2 += __uint_as_float(vA.y << 16);
                a3 += __uint_as_float(vA.y & 0xFFFF0000u);
                a0 += __uint_as_float(vB.x << 16);
                a1 += __uint_as_float(vB.x & 0xFFFF0000u);
                a2 += __uint_as_float(vB.y << 16);
                a3 += __uint_as_float(vB.y & 0xFFFF0000u);
            }
            a0 += __shfl_xor(a0, 16, 64); a0 += __shfl_xor(a0, 32, 64);
            a1 += __shfl_xor(a1, 16, 64); a1 += __shfl_xor(a1, 32, 64);
            a2 += __shfl_xor(a2, 16, 64); a2 += __shfl_xor(a2, 32, 64);
            a3 += __shfl_xor(a3, 16, 64); a3 += __shfl_xor(a3, 32, 64);
            if (quarter == 0) {
                float dv = (dcount > 0) ? rsqrtf((float)dcount) : 0.0f;
                float4 o;
                o.x = fmaxf(fmaf(a0, dv, bias.x), 0.f);
                o.y = fmaxf(fmaf(a1, dv, bias.y), 0.f);
                o.z = fmaxf(fmaf(a2, dv, bias.z), 0.f);
                o.w = fmaxf(fmaf(a3, dv, bias.w), 0.f);
                ((float4*)(out + (size_t)node * OUT_DIM))[qlane] = o;
            }
        }
    }
}

// ---------------------------------------------------------------------------
// Last-resort fallback (exotic sizes): atomic scatter, fp32 h
// ---------------------------------------------------------------------------
#define MM_NODES 16
__global__ void __launch_bounds__(256) k_matmul_f32(
    const float* __restrict__ x, const float* __restrict__ W,
    const float* __restrict__ dis, float* __restrict__ h, int n_nodes) {
    __shared__ float xs[MM_NODES * IN_DIM];
    const int lane = threadIdx.x & 63;
    const int wv = threadIdx.x >> 6;
    float w[IN_DIM];
#pragma unroll
    for (int k = 0; k < IN_DIM; ++k) w[k] = W[k * OUT_DIM + lane];
    int nchunks = (n_nodes + MM_NODES - 1) / MM_NODES;
    for (int ch = blockIdx.x; ch < nchunks; ch += gridDim.x) {
        int base = ch * MM_NODES;
        int nrows = min(MM_NODES, n_nodes - base);
        __syncthreads();
        const float4* xg = (const float4*)(x + (size_t)base * IN_DIM);
        int nf4 = nrows * IN_DIM / 4;
        for (int i = threadIdx.x; i < nf4; i += 256) ((float4*)xs)[i] = xg[i];
        __syncthreads();
#pragma unroll
        for (int j = 0; j < 4; ++j) {
            int local = wv * 4 + j;
            int node = base + local;
            if (local < nrows) {
                const float4* xr = (const float4*)(xs + local * IN_DIM);
                float acc = 0.0f;
#pragma unroll
                for (int k4 = 0; k4 < IN_DIM / 4; ++k4) {
                    float4 xv = xr[k4];
                    acc = fmaf(xv.x, w[k4 * 4 + 0], acc);
                    acc = fmaf(xv.y, w[k4 * 4 + 1], acc);
                    acc = fmaf(xv.z, w[k4 * 4 + 2], acc);
                    acc = fmaf(xv.w, w[k4 * 4 + 3], acc);
                }
                h[(size_t)node * OUT_DIM + lane] = acc * dis[node];
            }
        }
    }
}

__global__ void k_degree_fb(const int* __restrict__ col, int* __restrict__ deg,
                            int n_edges) {
    int i = blockIdx.x * blockDim.x + threadIdx.x;
    int stride = gridDim.x * blockDim.x;
    for (; i < n_edges; i += stride) atomicAdd(&deg[col[i]], 1);
}

__global__ void k_rsqrt_fb(const int* __restrict__ deg, float* __restrict__ dis, int n) {
    int i = blockIdx.x * blockDim.x + threadIdx.x;
    if (i < n) {
        int d = deg[i];
        dis[i] = (d > 0) ? rsqrtf((float)d) : 0.0f;
    }
}

__global__ void __launch_bounds__(256) k_scatter_fb(
    const int* __restrict__ row, const int* __restrict__ col,
    const float* __restrict__ dis, const float* __restrict__ h,
    float* __restrict__ out, int n_edges) {
    const int lane = threadIdx.x & 63;
    int e = (blockIdx.x * blockDim.x + threadIdx.x) >> 6;
    int nw = (gridDim.x * blockDim.x) >> 6;
    for (; e < n_edges; e += nw) {
        int r = row[e];
        int c = col[e];
        float v = h[(size_t)r * OUT_DIM + lane] * dis[c];
        atomicAdd(&out[(size_t)c * OUT_DIM + lane], v);
    }
}

__global__ void k_bias_relu_fb(float* __restrict__ out, const float* __restrict__ b,
                               int total) {
    int i = blockIdx.x * blockDim.x + threadIdx.x;
    int stride = gridDim.x * blockDim.x;
    for (; i < total; i += stride) {
        float v = out[i] + b[i & (OUT_DIM - 1)];
        out[i] = fmaxf(v, 0.0f);
    }
}

extern "C" void kernel_launch(void* const* d_in, const int* in_sizes, int n_in,
                              void* d_out, int out_size, void* d_ws, size_t ws_size,
                              hipStream_t stream) {
    const float* x = (const float*)d_in[0];
    const int* ei = (const int*)d_in[1];  // [2, E] int32
    const float* W = (const float*)d_in[2];
    const float* b = (const float*)d_in[3];
    float* out = (float*)d_out;

    const int n_nodes = in_sizes[0] / IN_DIM;
    const int n_edges = in_sizes[1] / 2;
    const int* row = ei;
    const int* col = ei + n_edges;

    const int nbf = (n_nodes + FNPB - 1) >> FLOG;   // fine buckets
    const int chunk = (n_edges + BB - 1) / BB;

    // ---- workspace layout (BinSize + cursors contiguous for one memset) ----
    char* wsb = (char*)d_ws;
    size_t off = 0;
    int* BinSize = (int*)(wsb + off);    off += (size_t)(nbf + 8) * 4;
    int* spillcur = BinSize + nbf;
    int* arenacur = BinSize + nbf + 1;
    const size_t zero_bytes = off;
    off = align_up(off, 256);
    unsigned int* EdgeBuf = (unsigned int*)(wsb + off);
                                         off += align_up((size_t)nbf * CAP * 4, 256);
    uint2* spill = (uint2*)(wsb + off);  off += align_up((size_t)SPILL_MAX * 8, 256);
    int* arena = (int*)(wsb + off);      off += align_up((size_t)n_edges * 4, 256);
    float* dis = (float*)(wsb + off);    off += align_up((size_t)n_nodes * 4, 256);
    unsigned short* h = (unsigned short*)(wsb + off);
                                         off += (size_t)n_nodes * OUT_DIM * 2;
    const size_t needed = off;

    const bool ok = (ws_size >= needed) && (nbf <= MAXFINE) &&
                    (chunk <= EBUF_MAX) && (n_nodes <= (1 << 24));

    if (ok) {
        hipMemsetAsync(BinSize, 0, zero_bytes, stream);
        kAB_build<<<BB, BT, 0, stream>>>(row, col, BinSize, EdgeBuf, spill,
                                         spillcur, n_edges, nbf, chunk);
        kD_degree<<<nbf, 256, 0, stream>>>(EdgeBuf, BinSize, spill, spillcur,
                                           dis, n_nodes);
        int ntiles = (n_nodes + 15) / 16;
        int mm_blocks = (ntiles + 3) / 4;
        k_matmul_mfma<<<mm_blocks, 256, 0, stream>>>(x, W, dis, h, n_nodes);
        kF_sortagg<<<nbf, 512, 0, stream>>>(EdgeBuf, BinSize, spill, spillcur,
                                            h, b, out, arena, arenacur, n_nodes);
    } else {
        // ---- last-resort fallback: atomic scatter, fp32 h ----
        char* p = (char*)d_ws;
        int* deg_f = (int*)p;
        float* dis_f = (float*)(p + align_up((size_t)n_nodes * 4, 256));
        float* h_f = (float*)(p + 2 * align_up((size_t)n_nodes * 4, 256));
        hipMemsetAsync(deg_f, 0, (size_t)n_nodes * 4, stream);
        hipMemsetAsync(out, 0, (size_t)out_size * 4, stream);
        k_degree_fb<<<1024, 256, 0, stream>>>(col, deg_f, n_edges);
        k_rsqrt_fb<<<(n_nodes + 255) / 256, 256, 0, stream>>>(deg_f, dis_f, n_nodes);
        k_matmul_f32<<<1024, 256, 0, stream>>>(x, W, dis_f, h_f, n_nodes);
        k_scatter_fb<<<2048, 256, 0, stream>>>(row, col, dis_f, h_f, out, n_edges);
        k_bias_relu_fb<<<2048, 256, 0, stream>>>(out, b, n_nodes * OUT_DIM);
    }
}